// Round 1
// baseline (490.883 us; speedup 1.0000x reference)
//
#include <hip/hip_runtime.h>
#include <hip/hip_bf16.h>

// Problem constants
#define T_TOK 2048      // B*S
#define DDIM  1024
#define EEXP  8
#define KTOP  2
#define HDIM  2816
#define HSDIM 1536
#define RTOT  4096      // T_TOK * KTOP

#define BK  64
#define LDK 72          // 64 + 8 bf16 pad -> row stride 144B, breaks 16-way conflicts

typedef float f32x4 __attribute__((ext_vector_type(4)));
typedef short bf16x8 __attribute__((ext_vector_type(8)));

__device__ inline unsigned short f2bf(float f) {
    __hip_bfloat16 h = __float2bfloat16(f);
    return __builtin_bit_cast(unsigned short, h);
}
__device__ inline unsigned int pack2(float a, float b) {
    return (unsigned int)f2bf(a) | ((unsigned int)f2bf(b) << 16);
}

// ---------------- small routing kernels ----------------

__global__ void init_k(int* counts, int* cursors) {
    if (threadIdx.x < EEXP) { counts[threadIdx.x] = 0; cursors[threadIdx.x] = 0; }
}

// one wave per token: 8 experts x 8 lane-chunks over D=1024
__global__ void gate_k(const float* __restrict__ X, const float* __restrict__ GW,
                       int* __restrict__ topi, float* __restrict__ topw,
                       int* __restrict__ counts) {
    int lane = threadIdx.x & 63;
    int t = blockIdx.x * 4 + (threadIdx.x >> 6);
    int e  = lane >> 3;   // expert handled by this lane
    int c8 = lane & 7;    // chunk within expert group
    const float* xr = X + (size_t)t * DDIM;
    const float* gr = GW + (size_t)e * DDIM;
    float acc = 0.f;
#pragma unroll 8
    for (int j = 0; j < 32; j++) {
        int d = (c8 + 8 * j) * 4;
        float4 xv = *(const float4*)(xr + d);
        float4 gv = *(const float4*)(gr + d);
        acc += xv.x * gv.x + xv.y * gv.y + xv.z * gv.z + xv.w * gv.w;
    }
    // reduce the 8 chunks of each expert (lanes e*8..e*8+7)
    acc += __shfl_xor(acc, 1);
    acc += __shfl_xor(acc, 2);
    acc += __shfl_xor(acc, 4);
    // broadcast all 8 logits to every lane
    float p[8];
#pragma unroll
    for (int q = 0; q < 8; q++) p[q] = __shfl(acc, q * 8);
    // softmax (f32, matches np within ~1e-7)
    float mx = p[0];
#pragma unroll
    for (int q = 1; q < 8; q++) mx = fmaxf(mx, p[q]);
    float s = 0.f;
#pragma unroll
    for (int q = 0; q < 8; q++) { p[q] = expf(p[q] - mx); s += p[q]; }
    float inv = 1.f / s;
#pragma unroll
    for (int q = 0; q < 8; q++) p[q] *= inv;
    // top-2, stable (ties -> lower index, np.top_k behavior)
    float v1 = -1.f; int i1 = 0;
#pragma unroll
    for (int q = 0; q < 8; q++) { if (p[q] > v1) { v1 = p[q]; i1 = q; } }
    float v2 = -1.f; int i2 = 0;
#pragma unroll
    for (int q = 0; q < 8; q++) { if (q != i1 && p[q] > v2) { v2 = p[q]; i2 = q; } }
    if (lane == 0) {
        topi[2 * t] = i1; topi[2 * t + 1] = i2;
        topw[2 * t] = v1; topw[2 * t + 1] = v2;
        atomicAdd(&counts[i1], 1);
        atomicAdd(&counts[i2], 1);
    }
}

__global__ void scan_k(const int* __restrict__ counts, int* __restrict__ offsets) {
    if (threadIdx.x == 0) {
        int s = 0;
        for (int e = 0; e < EEXP; e++) { offsets[e] = s; s += counts[e]; }
        offsets[EEXP] = s;   // == RTOT
    }
}

__global__ void build_k(const int* __restrict__ topi, const int* __restrict__ offsets,
                        int* __restrict__ cursors, int* __restrict__ rows_token,
                        int* __restrict__ rowof) {
    int t = blockIdx.x * 256 + threadIdx.x;
    if (t >= T_TOK) return;
    for (int k = 0; k < KTOP; k++) {
        int e = topi[2 * t + k];
        int pos = atomicAdd(&cursors[e], 1);
        int r = offsets[e] + pos;
        rows_token[r] = t;
        rowof[2 * t + k] = r;
    }
}

// ---------------- fused up-projection: H = silu(X@W1) * (X@W3) ----------------
// tile 128(M) x 64(N), BK=64, 4 waves in 2x2, per-wave 64x32 dual-accumulated.
// offsets==null -> identity mode (shared expert): rows are tokens, Ne=Mtot.
__global__ __launch_bounds__(256) void fused_up(
    const float* __restrict__ X,
    const int* __restrict__ rows_token,
    const int* __restrict__ offsets,
    const float* __restrict__ W1,
    const float* __restrict__ W3,
    unsigned short* __restrict__ Hout,   // bf16 bits, [rows][Nn]
    int Kd, int Nn, int Mtot)
{
    int e = blockIdx.z;
    int roff, Ne;
    if (offsets) { roff = offsets[e]; Ne = offsets[e + 1] - roff; }
    else         { roff = 0;          Ne = Mtot; }
    int m0 = blockIdx.y * 128;
    if (m0 >= Ne) return;
    int n0 = blockIdx.x * 64;
    const float* w1 = W1 + (size_t)e * Kd * Nn;
    const float* w3 = W3 + (size_t)e * Kd * Nn;

    __shared__ __align__(16) unsigned short As [128][LDK];
    __shared__ __align__(16) unsigned short Bs1[64][LDK];
    __shared__ __align__(16) unsigned short Bs3[64][LDK];

    int tid = threadIdx.x;
    int lane = tid & 63, wid = tid >> 6;
    int wr = wid >> 1, wc = wid & 1;     // wave tile: rows wr*64.., cols wc*32..

    const f32x4 fz = {0.f, 0.f, 0.f, 0.f};
    f32x4 acc1[4][2], acc3[4][2];
#pragma unroll
    for (int mi = 0; mi < 4; mi++)
#pragma unroll
        for (int ni = 0; ni < 2; ni++) { acc1[mi][ni] = fz; acc3[mi][ni] = fz; }

    // staging maps (hoisted)
    int arow_sub = tid >> 4;            // 0..15
    int akq = (tid & 15) * 4;           // k quad for A
    int bn = (tid & 15) * 4;            // n base for B transpose block
    int bkk = (tid >> 4) * 4;           // k base for B transpose block
    int tok[8];
#pragma unroll
    for (int p = 0; p < 8; p++) {
        int gr = m0 + p * 16 + arow_sub;
        if (gr >= Ne) gr = Ne - 1;
        tok[p] = rows_token ? rows_token[roff + gr] : gr;
    }

    for (int k0 = 0; k0 < Kd; k0 += BK) {
        __syncthreads();
        // stage A: x rows -> bf16 [m][k]
#pragma unroll
        for (int p = 0; p < 8; p++) {
            int row = p * 16 + arow_sub;
            const float4 v = *(const float4*)(X + (size_t)tok[p] * Kd + k0 + akq);
            *(uint2*)&As[row][akq] = make_uint2(pack2(v.x, v.y), pack2(v.z, v.w));
        }
        // stage B1/B3: w[k][n] -> bf16 [n][k] (4x4 register transpose)
        {
            const float* p1 = w1 + (size_t)(k0 + bkk) * Nn + n0 + bn;
            float4 q0 = *(const float4*)(p1);
            float4 q1 = *(const float4*)(p1 + (size_t)Nn);
            float4 q2 = *(const float4*)(p1 + 2 * (size_t)Nn);
            float4 q3 = *(const float4*)(p1 + 3 * (size_t)Nn);
#pragma unroll
            for (int j = 0; j < 4; j++) {
                *(uint2*)&Bs1[bn + j][bkk] =
                    make_uint2(pack2((&q0.x)[j], (&q1.x)[j]), pack2((&q2.x)[j], (&q3.x)[j]));
            }
            const float* p3 = w3 + (size_t)(k0 + bkk) * Nn + n0 + bn;
            q0 = *(const float4*)(p3);
            q1 = *(const float4*)(p3 + (size_t)Nn);
            q2 = *(const float4*)(p3 + 2 * (size_t)Nn);
            q3 = *(const float4*)(p3 + 3 * (size_t)Nn);
#pragma unroll
            for (int j = 0; j < 4; j++) {
                *(uint2*)&Bs3[bn + j][bkk] =
                    make_uint2(pack2((&q0.x)[j], (&q1.x)[j]), pack2((&q2.x)[j], (&q3.x)[j]));
            }
        }
        __syncthreads();
#pragma unroll
        for (int kk = 0; kk < 2; kk++) {
            int krd = kk * 32 + (lane >> 4) * 8;
            bf16x8 a[4];
#pragma unroll
            for (int mi = 0; mi < 4; mi++)
                a[mi] = *(const bf16x8*)&As[wr * 64 + mi * 16 + (lane & 15)][krd];
            bf16x8 b1v[2], b3v[2];
#pragma unroll
            for (int ni = 0; ni < 2; ni++) {
                b1v[ni] = *(const bf16x8*)&Bs1[wc * 32 + ni * 16 + (lane & 15)][krd];
                b3v[ni] = *(const bf16x8*)&Bs3[wc * 32 + ni * 16 + (lane & 15)][krd];
            }
#pragma unroll
            for (int mi = 0; mi < 4; mi++)
#pragma unroll
                for (int ni = 0; ni < 2; ni++) {
                    acc1[mi][ni] = __builtin_amdgcn_mfma_f32_16x16x32_bf16(a[mi], b1v[ni], acc1[mi][ni], 0, 0, 0);
                    acc3[mi][ni] = __builtin_amdgcn_mfma_f32_16x16x32_bf16(a[mi], b3v[ni], acc3[mi][ni], 0, 0, 0);
                }
        }
    }
    // epilogue: h = silu(a)*b, store bf16
#pragma unroll
    for (int mi = 0; mi < 4; mi++) {
        int rloc = wr * 64 + mi * 16 + ((lane >> 4) * 4);
#pragma unroll
        for (int ni = 0; ni < 2; ni++) {
            int col = n0 + wc * 32 + ni * 16 + (lane & 15);
#pragma unroll
            for (int j = 0; j < 4; j++) {
                int row = rloc + j;
                if (m0 + row < Ne) {
                    float a = acc1[mi][ni][j];
                    float b = acc3[mi][ni][j];
                    float h = (a / (1.f + expf(-a))) * b;
                    Hout[(size_t)(roff + m0 + row) * Nn + col] = f2bf(h);
                }
            }
        }
    }
}

// ---------------- down-projection: Y = H @ W2 ----------------
// tile 64(M) x 128(N), BK=64, 4 waves side-by-side (each 64x32).
// direct=1 -> write rows as tokens into out (shared expert); else into Yg at roff+row.
__global__ __launch_bounds__(256) void gemm2(
    const unsigned short* __restrict__ Ain,  // bf16 bits [rows][Kd]
    const float* __restrict__ W,             // [e][Kd][Nn]
    const int* __restrict__ offsets,
    float* __restrict__ Yout,
    int Kd, int Nn, int Mtot, int direct)
{
    int e = blockIdx.z;
    int roff, Ne;
    if (offsets) { roff = offsets[e]; Ne = offsets[e + 1] - roff; }
    else         { roff = 0;          Ne = Mtot; }
    int m0 = blockIdx.y * 64;
    if (m0 >= Ne) return;
    int n0 = blockIdx.x * 128;
    const float* w = W + (size_t)e * Kd * Nn;

    __shared__ __align__(16) unsigned short As[64][LDK];
    __shared__ __align__(16) unsigned short Bs[128][LDK];

    int tid = threadIdx.x;
    int lane = tid & 63, wid = tid >> 6;
    int wc = wid;                        // wave tile: all 64 rows x cols wc*32..

    const f32x4 fz = {0.f, 0.f, 0.f, 0.f};
    f32x4 acc[4][2];
#pragma unroll
    for (int mi = 0; mi < 4; mi++)
#pragma unroll
        for (int ni = 0; ni < 2; ni++) acc[mi][ni] = fz;

    int arow_sub = tid >> 3;   // 0..31
    int akq = (tid & 7) * 8;   // 8 bf16 = 16B
    int grow[2];
#pragma unroll
    for (int p = 0; p < 2; p++) {
        int gr = m0 + p * 32 + arow_sub;
        if (gr >= Ne) gr = Ne - 1;
        grow[p] = roff + gr;
    }

    for (int k0 = 0; k0 < Kd; k0 += BK) {
        __syncthreads();
        // stage A (already bf16): direct 16B copies
#pragma unroll
        for (int p = 0; p < 2; p++) {
            int row = p * 32 + arow_sub;
            *(uint4*)&As[row][akq] = *(const uint4*)(Ain + (size_t)grow[p] * Kd + k0 + akq);
        }
        // stage B: w[k][n] -> [n][k], 2 transpose blocks per thread
#pragma unroll
        for (int h = 0; h < 2; h++) {
            int blk = tid + h * 256;
            int nb = (blk & 31) * 4;
            int kb = (blk >> 5) * 4;
            const float* p0 = w + (size_t)(k0 + kb) * Nn + n0 + nb;
            float4 q0 = *(const float4*)(p0);
            float4 q1 = *(const float4*)(p0 + (size_t)Nn);
            float4 q2 = *(const float4*)(p0 + 2 * (size_t)Nn);
            float4 q3 = *(const float4*)(p0 + 3 * (size_t)Nn);
#pragma unroll
            for (int j = 0; j < 4; j++) {
                *(uint2*)&Bs[nb + j][kb] =
                    make_uint2(pack2((&q0.x)[j], (&q1.x)[j]), pack2((&q2.x)[j], (&q3.x)[j]));
            }
        }
        __syncthreads();
#pragma unroll
        for (int kk = 0; kk < 2; kk++) {
            int krd = kk * 32 + (lane >> 4) * 8;
            bf16x8 a[4], b[2];
#pragma unroll
            for (int mi = 0; mi < 4; mi++)
                a[mi] = *(const bf16x8*)&As[mi * 16 + (lane & 15)][krd];
#pragma unroll
            for (int ni = 0; ni < 2; ni++)
                b[ni] = *(const bf16x8*)&Bs[wc * 32 + ni * 16 + (lane & 15)][krd];
#pragma unroll
            for (int mi = 0; mi < 4; mi++)
#pragma unroll
                for (int ni = 0; ni < 2; ni++)
                    acc[mi][ni] = __builtin_amdgcn_mfma_f32_16x16x32_bf16(a[mi], b[ni], acc[mi][ni], 0, 0, 0);
        }
    }
#pragma unroll
    for (int mi = 0; mi < 4; mi++) {
        int rloc = mi * 16 + ((lane >> 4) * 4);
#pragma unroll
        for (int ni = 0; ni < 2; ni++) {
            int col = n0 + wc * 32 + ni * 16 + (lane & 15);
#pragma unroll
            for (int j = 0; j < 4; j++) {
                int row = rloc + j;
                if (m0 + row < Ne) {
                    size_t orow = direct ? (size_t)(m0 + row) : (size_t)(roff + m0 + row);
                    Yout[orow * Nn + col] = acc[mi][ni][j];
                }
            }
        }
    }
}

// ---------------- final combine: out += g0*Y[row(t,0)] + g1*Y[row(t,1)] ----------------
__global__ void combine_k(float* __restrict__ out, const float* __restrict__ Yg,
                          const int* __restrict__ rowof, const float* __restrict__ topw) {
    int idx = blockIdx.x * 256 + threadIdx.x;       // T_TOK*DDIM/4 total
    int t = idx >> 8;
    int dq = (idx & 255) << 2;
    int r0 = rowof[2 * t], r1 = rowof[2 * t + 1];
    float g0 = topw[2 * t], g1 = topw[2 * t + 1];
    float* op = out + (size_t)t * DDIM + dq;
    float4 o = *(float4*)op;
    float4 a = *(const float4*)(Yg + (size_t)r0 * DDIM + dq);
    float4 b = *(const float4*)(Yg + (size_t)r1 * DDIM + dq);
    o.x += g0 * a.x + g1 * b.x;
    o.y += g0 * a.y + g1 * b.y;
    o.z += g0 * a.z + g1 * b.z;
    o.w += g0 * a.w + g1 * b.w;
    *(float4*)op = o;
}

// ---------------- launch ----------------
extern "C" void kernel_launch(void* const* d_in, const int* in_sizes, int n_in,
                              void* d_out, int out_size, void* d_ws, size_t ws_size,
                              hipStream_t stream) {
    const float* x   = (const float*)d_in[0];
    const float* gw  = (const float*)d_in[1];
    const float* w1  = (const float*)d_in[2];
    const float* w3  = (const float*)d_in[3];
    const float* w2  = (const float*)d_in[4];
    const float* sw1 = (const float*)d_in[5];
    const float* sw3 = (const float*)d_in[6];
    const float* sw2 = (const float*)d_in[7];
    float* out = (float*)d_out;
    char* ws = (char*)d_ws;

    int*   counts     = (int*)(ws);
    int*   offsets    = (int*)(ws + 64);
    int*   cursors    = (int*)(ws + 128);
    int*   topi       = (int*)(ws + 512);
    float* topw       = (float*)(ws + 512 + 16384);
    int*   rows_token = (int*)(ws + 512 + 2 * 16384);
    int*   rowof      = (int*)(ws + 512 + 3 * 16384);
    unsigned short* Hg = (unsigned short*)(ws + 82944);                       // [4096][2816] bf16
    float*          Yg = (float*)(ws + 82944 + 23068672);                     // [4096][1024] f32
    unsigned short* Hs = (unsigned short*)(ws + 82944 + 23068672 + 16777216); // [2048][1536] bf16

    init_k<<<1, 64, 0, stream>>>(counts, cursors);
    gate_k<<<T_TOK / 4, 256, 0, stream>>>(x, gw, topi, topw, counts);
    scan_k<<<1, 64, 0, stream>>>(counts, offsets);
    build_k<<<T_TOK / 256, 256, 0, stream>>>(topi, offsets, cursors, rows_token, rowof);

    // routed experts: up (fused w1/w3+silu) then down
    fused_up<<<dim3(HDIM / 64, T_TOK / 128, EEXP), 256, 0, stream>>>(
        x, rows_token, offsets, w1, w3, Hg, DDIM, HDIM, 0);
    gemm2<<<dim3(DDIM / 128, T_TOK / 64, EEXP), 256, 0, stream>>>(
        Hg, w2, offsets, Yg, HDIM, DDIM, 0, 0);

    // shared expert: up then down (writes out directly)
    fused_up<<<dim3(HSDIM / 64, T_TOK / 128, 1), 256, 0, stream>>>(
        x, nullptr, nullptr, sw1, sw3, Hs, DDIM, HSDIM, T_TOK);
    gemm2<<<dim3(DDIM / 128, T_TOK / 64, 1), 256, 0, stream>>>(
        Hs, sw2, nullptr, out, HSDIM, DDIM, T_TOK, 1);

    // out = shared + g0*y0 + g1*y1
    combine_k<<<(T_TOK * DDIM / 4) / 256, 256, 0, stream>>>(out, Yg, rowof, topw);
}

// Round 2
// 335.426 us; speedup vs baseline: 1.4635x; 1.4635x over previous
//
#include <hip/hip_runtime.h>
#include <hip/hip_bf16.h>

// Problem constants
#define T_TOK 2048      // B*S
#define DDIM  1024
#define EEXP  8
#define KTOP  2
#define HDIM  2816
#define HSDIM 1536
#define BK    64

typedef float f32x4 __attribute__((ext_vector_type(4)));
typedef short bf16x8 __attribute__((ext_vector_type(8)));

__device__ __forceinline__ unsigned short f2bf(float f) {
    __hip_bfloat16 h = __float2bfloat16(f);
    return __builtin_bit_cast(unsigned short, h);
}

// async global->LDS, 16B per lane; LDS dest = wave-uniform base + lane*16
__device__ __forceinline__ void gload16(const unsigned short* g, unsigned short* l) {
    __builtin_amdgcn_global_load_lds(
        (const __attribute__((address_space(1))) unsigned int*)g,
        (__attribute__((address_space(3))) unsigned int*)l, 16, 0, 0);
}

// ---------------- small routing kernels ----------------

__global__ void init_k(int* counts, int* cursors) {
    if (threadIdx.x < EEXP) { counts[threadIdx.x] = 0; cursors[threadIdx.x] = 0; }
}

// one wave per token: 8 experts x 8 lane-chunks over D=1024
__global__ void gate_k(const float* __restrict__ X, const float* __restrict__ GW,
                       int* __restrict__ topi, float* __restrict__ topw,
                       int* __restrict__ counts) {
    int lane = threadIdx.x & 63;
    int t = blockIdx.x * 4 + (threadIdx.x >> 6);
    int e  = lane >> 3;
    int c8 = lane & 7;
    const float* xr = X + (size_t)t * DDIM;
    const float* gr = GW + (size_t)e * DDIM;
    float acc = 0.f;
#pragma unroll 8
    for (int j = 0; j < 32; j++) {
        int d = (c8 + 8 * j) * 4;
        float4 xv = *(const float4*)(xr + d);
        float4 gv = *(const float4*)(gr + d);
        acc += xv.x * gv.x + xv.y * gv.y + xv.z * gv.z + xv.w * gv.w;
    }
    acc += __shfl_xor(acc, 1);
    acc += __shfl_xor(acc, 2);
    acc += __shfl_xor(acc, 4);
    float p[8];
#pragma unroll
    for (int q = 0; q < 8; q++) p[q] = __shfl(acc, q * 8);
    float mx = p[0];
#pragma unroll
    for (int q = 1; q < 8; q++) mx = fmaxf(mx, p[q]);
    float s = 0.f;
#pragma unroll
    for (int q = 0; q < 8; q++) { p[q] = expf(p[q] - mx); s += p[q]; }
    float inv = 1.f / s;
#pragma unroll
    for (int q = 0; q < 8; q++) p[q] *= inv;
    float v1 = -1.f; int i1 = 0;
#pragma unroll
    for (int q = 0; q < 8; q++) { if (p[q] > v1) { v1 = p[q]; i1 = q; } }
    float v2 = -1.f; int i2 = 0;
#pragma unroll
    for (int q = 0; q < 8; q++) { if (q != i1 && p[q] > v2) { v2 = p[q]; i2 = q; } }
    if (lane == 0) {
        topi[2 * t] = i1; topi[2 * t + 1] = i2;
        topw[2 * t] = v1; topw[2 * t + 1] = v2;
        atomicAdd(&counts[i1], 1);
        atomicAdd(&counts[i2], 1);
    }
}

__global__ void scan_k(const int* __restrict__ counts, int* __restrict__ offsets) {
    if (threadIdx.x == 0) {
        int s = 0;
        for (int e = 0; e < EEXP; e++) { offsets[e] = s; s += counts[e]; }
        offsets[EEXP] = s;
    }
}

__global__ void build_k(const int* __restrict__ topi, const int* __restrict__ offsets,
                        int* __restrict__ cursors, int* __restrict__ rows_token,
                        int* __restrict__ rowof) {
    int t = blockIdx.x * 256 + threadIdx.x;
    if (t >= T_TOK) return;
    for (int k = 0; k < KTOP; k++) {
        int e = topi[2 * t + k];
        int pos = atomicAdd(&cursors[e], 1);
        int r = offsets[e] + pos;
        rows_token[r] = t;
        rowof[2 * t + k] = r;
    }
}

// ---------------- pre-pass: casts & transposes ----------------

// X f32 -> bf16, same layout
__global__ void xcast_k(const float* __restrict__ X, unsigned short* __restrict__ Xb) {
    int i = (blockIdx.x * 256 + threadIdx.x) * 8;
    float4 a = *(const float4*)(X + i);
    float4 b = *(const float4*)(X + i + 4);
    unsigned short o[8] = { f2bf(a.x), f2bf(a.y), f2bf(a.z), f2bf(a.w),
                            f2bf(b.x), f2bf(b.y), f2bf(b.z), f2bf(b.w) };
    *(uint4*)(Xb + i) = *(const uint4*)o;
}

// W [z][K][N] f32 -> Wt [z][N][K] bf16, 64x64 tiles via LDS
__global__ __launch_bounds__(256) void tcast_k(const float* __restrict__ S,
                                               unsigned short* __restrict__ Dm,
                                               int Kd, int Nn) {
    size_t zoff = (size_t)blockIdx.z * Kd * Nn;
    S += zoff; Dm += zoff;
    int k0 = blockIdx.y * 64, n0 = blockIdx.x * 64;
    __shared__ __align__(16) unsigned short t[64][72];
    int tid = threadIdx.x;
    int kr = tid >> 4;            // 0..15
    int nc = (tid & 15) * 4;
#pragma unroll
    for (int j = 0; j < 4; j++) {
        int k = j * 16 + kr;
        float4 v = *(const float4*)(S + (size_t)(k0 + k) * Nn + n0 + nc);
        t[nc + 0][k] = f2bf(v.x);
        t[nc + 1][k] = f2bf(v.y);
        t[nc + 2][k] = f2bf(v.z);
        t[nc + 3][k] = f2bf(v.w);
    }
    __syncthreads();
    int n = tid >> 3;             // 0..31
    int c = (tid & 7) * 8;
#pragma unroll
    for (int j = 0; j < 2; j++) {
        int nn = j * 32 + n;
        *(uint4*)(Dm + (size_t)(n0 + nn) * Kd + k0 + c) = *(const uint4*)&t[nn][c];
    }
}

// ---------------- fused up-projection: H = silu(X@W1) * (X@W3) ----------------
// tile 128(M) x 64(N), BK=64; z=0..7 routed experts, z=8 shared expert.
// A,B staged via global_load_lds into linear 128B rows; XOR swizzle (chunk^=row&7)
// applied on the per-lane GLOBAL source and on the ds_read address (rule #21).
__global__ __launch_bounds__(256) void fused_up(
    const unsigned short* __restrict__ Xb,
    const int* __restrict__ rows_token,
    const int* __restrict__ offsets,
    const unsigned short* __restrict__ W1t,   // [8][H][D] bf16
    const unsigned short* __restrict__ W3t,
    const unsigned short* __restrict__ sw1t,  // [HS][D]
    const unsigned short* __restrict__ sw3t,
    unsigned short* __restrict__ Hg,          // [4096][H]
    unsigned short* __restrict__ Hs)          // [2048][HS]
{
    int z = blockIdx.z;
    bool sh = (z == EEXP);
    int roff, Ne, Nn;
    const unsigned short *w1, *w3;
    unsigned short* Ho;
    if (sh) { roff = 0; Ne = T_TOK; Nn = HSDIM; w1 = sw1t; w3 = sw3t; Ho = Hs; }
    else {
        roff = offsets[z]; Ne = offsets[z + 1] - roff;
        Nn = HDIM;
        w1 = W1t + (size_t)z * HDIM * DDIM;
        w3 = W3t + (size_t)z * HDIM * DDIM;
        Ho = Hg;
    }
    int n0 = blockIdx.x * 64;
    if (n0 >= Nn) return;
    int m0 = blockIdx.y * 128;
    if (m0 >= Ne) return;

    __shared__ __align__(16) unsigned short As[128 * 64];
    __shared__ __align__(16) unsigned short B1s[64 * 64];
    __shared__ __align__(16) unsigned short B3s[64 * 64];

    int tid = threadIdx.x, lane = tid & 63, wid = tid >> 6;
    int wr = wid >> 1, wc = wid & 1;          // per-wave 64 rows x 32 cols

    int sc = ((lane & 7) ^ (lane >> 3)) * 8;  // inverse-swizzled source chunk (u16 units)

    const unsigned short* pA[4];
#pragma unroll
    for (int j = 0; j < 4; j++) {
        int lr = (wid * 4 + j) * 8 + (lane >> 3);
        int gr = m0 + lr; if (gr >= Ne) gr = Ne - 1;
        int tok = sh ? gr : rows_token[roff + gr];
        pA[j] = Xb + (size_t)tok * DDIM + sc;
    }
    const unsigned short *pB1[2], *pB3[2];
#pragma unroll
    for (int j = 0; j < 2; j++) {
        int lr = (wid * 2 + j) * 8 + (lane >> 3);
        pB1[j] = w1 + (size_t)(n0 + lr) * DDIM + sc;
        pB3[j] = w3 + (size_t)(n0 + lr) * DDIM + sc;
    }

    const f32x4 fz = {0.f, 0.f, 0.f, 0.f};
    f32x4 acc1[4][2], acc3[4][2];
#pragma unroll
    for (int mi = 0; mi < 4; mi++)
#pragma unroll
        for (int nj = 0; nj < 2; nj++) { acc1[mi][nj] = fz; acc3[mi][nj] = fz; }

#pragma unroll 1
    for (int ks = 0; ks < DDIM / BK; ks++) {
        __syncthreads();
#pragma unroll
        for (int j = 0; j < 4; j++) gload16(pA[j], As + (wid * 4 + j) * 512);
#pragma unroll
        for (int j = 0; j < 2; j++) {
            gload16(pB1[j], B1s + (wid * 2 + j) * 512);
            gload16(pB3[j], B3s + (wid * 2 + j) * 512);
        }
#pragma unroll
        for (int j = 0; j < 4; j++) pA[j] += BK;
#pragma unroll
        for (int j = 0; j < 2; j++) { pB1[j] += BK; pB3[j] += BK; }
        __syncthreads();
        int r = lane & 15, h = lane >> 4, sw = (lane & 7) << 4;
#pragma unroll
        for (int kk = 0; kk < 2; kk++) {
            int cb = (kk * 64 + h * 16) ^ sw;  // physical byte within 128B row
            bf16x8 a[4], b1[2], b3[2];
#pragma unroll
            for (int mi = 0; mi < 4; mi++)
                a[mi] = *(const bf16x8*)((const char*)As + (wr * 64 + mi * 16 + r) * 128 + cb);
#pragma unroll
            for (int nj = 0; nj < 2; nj++) {
                b1[nj] = *(const bf16x8*)((const char*)B1s + (wc * 32 + nj * 16 + r) * 128 + cb);
                b3[nj] = *(const bf16x8*)((const char*)B3s + (wc * 32 + nj * 16 + r) * 128 + cb);
            }
#pragma unroll
            for (int mi = 0; mi < 4; mi++)
#pragma unroll
                for (int nj = 0; nj < 2; nj++) {
                    acc1[mi][nj] = __builtin_amdgcn_mfma_f32_16x16x32_bf16(a[mi], b1[nj], acc1[mi][nj], 0, 0, 0);
                    acc3[mi][nj] = __builtin_amdgcn_mfma_f32_16x16x32_bf16(a[mi], b3[nj], acc3[mi][nj], 0, 0, 0);
                }
        }
    }
    int r = lane & 15, h = lane >> 4;
#pragma unroll
    for (int mi = 0; mi < 4; mi++) {
#pragma unroll
        for (int nj = 0; nj < 2; nj++) {
            int col = n0 + wc * 32 + nj * 16 + r;
#pragma unroll
            for (int j = 0; j < 4; j++) {
                int row = wr * 64 + mi * 16 + h * 4 + j;
                if (m0 + row < Ne) {
                    float aa = acc1[mi][nj][j], bb = acc3[mi][nj][j];
                    float hv = (aa / (1.f + expf(-aa))) * bb;
                    Ho[(size_t)(roff + m0 + row) * Nn + col] = f2bf(hv);
                }
            }
        }
    }
}

// ---------------- down-projection: Y = H @ W2 ----------------
// tile 64(M) x 128(N), BK=64; z=0..7 routed (-> Yg), z=8 shared (-> out direct).
__global__ __launch_bounds__(256) void gemm2(
    const unsigned short* __restrict__ Hg,
    const unsigned short* __restrict__ Hs,
    const unsigned short* __restrict__ W2t,   // [8][D][H] bf16
    const unsigned short* __restrict__ sw2t,  // [D][HS]
    const int* __restrict__ offsets,
    float* __restrict__ Yg,
    float* __restrict__ out)
{
    int z = blockIdx.z;
    bool sh = (z == EEXP);
    int roff, Ne, Kd;
    const unsigned short *Ab, *Bb;
    float* Yo;
    if (sh) { roff = 0; Ne = T_TOK; Kd = HSDIM; Ab = Hs; Bb = sw2t; Yo = out; }
    else {
        roff = offsets[z]; Ne = offsets[z + 1] - roff; Kd = HDIM;
        Ab = Hg + (size_t)roff * HDIM;
        Bb = W2t + (size_t)z * DDIM * HDIM;
        Yo = Yg + (size_t)roff * DDIM;
    }
    int m0 = blockIdx.y * 64;
    if (m0 >= Ne) return;
    int n0 = blockIdx.x * 128;

    __shared__ __align__(16) unsigned short As[64 * 64];
    __shared__ __align__(16) unsigned short Bs[128 * 64];

    int tid = threadIdx.x, lane = tid & 63, wid = tid >> 6;
    int wr = wid >> 1, wc = wid & 1;          // per-wave 32 rows x 64 cols
    int sc = ((lane & 7) ^ (lane >> 3)) * 8;

    const unsigned short* pA[2];
#pragma unroll
    for (int j = 0; j < 2; j++) {
        int lr = (wid * 2 + j) * 8 + (lane >> 3);
        int gr = m0 + lr; if (gr >= Ne) gr = Ne - 1;
        pA[j] = Ab + (size_t)gr * Kd + sc;
    }
    const unsigned short* pB[4];
#pragma unroll
    for (int j = 0; j < 4; j++) {
        int lr = (wid * 4 + j) * 8 + (lane >> 3);
        pB[j] = Bb + (size_t)(n0 + lr) * Kd + sc;
    }

    const f32x4 fz = {0.f, 0.f, 0.f, 0.f};
    f32x4 acc[2][4];
#pragma unroll
    for (int mi = 0; mi < 2; mi++)
#pragma unroll
        for (int nj = 0; nj < 4; nj++) acc[mi][nj] = fz;

    int nks = Kd / BK;
#pragma unroll 1
    for (int ks = 0; ks < nks; ks++) {
        __syncthreads();
#pragma unroll
        for (int j = 0; j < 2; j++) gload16(pA[j], As + (wid * 2 + j) * 512);
#pragma unroll
        for (int j = 0; j < 4; j++) gload16(pB[j], Bs + (wid * 4 + j) * 512);
#pragma unroll
        for (int j = 0; j < 2; j++) pA[j] += BK;
#pragma unroll
        for (int j = 0; j < 4; j++) pB[j] += BK;
        __syncthreads();
        int r = lane & 15, h = lane >> 4, sw = (lane & 7) << 4;
#pragma unroll
        for (int kk = 0; kk < 2; kk++) {
            int cb = (kk * 64 + h * 16) ^ sw;
            bf16x8 a[2], b[4];
#pragma unroll
            for (int mi = 0; mi < 2; mi++)
                a[mi] = *(const bf16x8*)((const char*)As + (wr * 32 + mi * 16 + r) * 128 + cb);
#pragma unroll
            for (int nj = 0; nj < 4; nj++)
                b[nj] = *(const bf16x8*)((const char*)Bs + (wc * 64 + nj * 16 + r) * 128 + cb);
#pragma unroll
            for (int mi = 0; mi < 2; mi++)
#pragma unroll
                for (int nj = 0; nj < 4; nj++)
                    acc[mi][nj] = __builtin_amdgcn_mfma_f32_16x16x32_bf16(a[mi], b[nj], acc[mi][nj], 0, 0, 0);
        }
    }
    int r = lane & 15, h = lane >> 4;
#pragma unroll
    for (int mi = 0; mi < 2; mi++) {
#pragma unroll
        for (int nj = 0; nj < 4; nj++) {
            int col = n0 + wc * 64 + nj * 16 + r;
#pragma unroll
            for (int j = 0; j < 4; j++) {
                int row = wr * 32 + mi * 16 + h * 4 + j;
                if (m0 + row < Ne)
                    Yo[(size_t)(m0 + row) * DDIM + col] = acc[mi][nj][j];
            }
        }
    }
}

// ---------------- final combine ----------------
__global__ void combine_k(float* __restrict__ out, const float* __restrict__ Yg,
                          const int* __restrict__ rowof, const float* __restrict__ topw) {
    int idx = blockIdx.x * 256 + threadIdx.x;
    int t = idx >> 8;
    int dq = (idx & 255) << 2;
    int r0 = rowof[2 * t], r1 = rowof[2 * t + 1];
    float g0 = topw[2 * t], g1 = topw[2 * t + 1];
    float* op = out + (size_t)t * DDIM + dq;
    float4 o = *(float4*)op;
    float4 a = *(const float4*)(Yg + (size_t)r0 * DDIM + dq);
    float4 b = *(const float4*)(Yg + (size_t)r1 * DDIM + dq);
    o.x += g0 * a.x + g1 * b.x;
    o.y += g0 * a.y + g1 * b.y;
    o.z += g0 * a.z + g1 * b.z;
    o.w += g0 * a.w + g1 * b.w;
    *(float4*)op = o;
}

// ---------------- launch ----------------
extern "C" void kernel_launch(void* const* d_in, const int* in_sizes, int n_in,
                              void* d_out, int out_size, void* d_ws, size_t ws_size,
                              hipStream_t stream) {
    const float* x   = (const float*)d_in[0];
    const float* gw  = (const float*)d_in[1];
    const float* w1  = (const float*)d_in[2];
    const float* w3  = (const float*)d_in[3];
    const float* w2  = (const float*)d_in[4];
    const float* sw1 = (const float*)d_in[5];
    const float* sw3 = (const float*)d_in[6];
    const float* sw2 = (const float*)d_in[7];
    float* out = (float*)d_out;
    char* ws = (char*)d_ws;

    const size_t MB = 1048576;
    int*   counts     = (int*)(ws);
    int*   offsets    = (int*)(ws + 64);
    int*   cursors    = (int*)(ws + 128);
    int*   topi       = (int*)(ws + 512);
    float* topw       = (float*)(ws + 16896);
    int*   rows_token = (int*)(ws + 33280);
    int*   rowof      = (int*)(ws + 49664);
    unsigned short* Xb   = (unsigned short*)(ws + 1 * MB);    // 4 MB
    unsigned short* sw1t = (unsigned short*)(ws + 6 * MB);    // 3 MB
    unsigned short* sw3t = (unsigned short*)(ws + 9 * MB);    // 3 MB
    unsigned short* sw2t = (unsigned short*)(ws + 12 * MB);   // 3 MB
    unsigned short* Hg   = (unsigned short*)(ws + 16 * MB);   // 22 MB
    float*          Yg   = (float*)(ws + 40 * MB);            // 16 MB
    unsigned short* Hs   = (unsigned short*)(ws + 56 * MB);   // 6 MB
    unsigned short* W1t  = (unsigned short*)(ws + 64 * MB);   // 44 MB
    unsigned short* W3t  = (unsigned short*)(ws + 108 * MB);  // 44 MB (ends 152 MB)
    unsigned short* W2t  = W1t;  // aliased: converted after fused_up consumes W1t

    // routing
    init_k<<<1, 64, 0, stream>>>(counts, cursors);
    gate_k<<<T_TOK / 4, 256, 0, stream>>>(x, gw, topi, topw, counts);
    scan_k<<<1, 64, 0, stream>>>(counts, offsets);
    build_k<<<T_TOK / 256, 256, 0, stream>>>(topi, offsets, cursors, rows_token, rowof);

    // pre-pass: bf16 casts + weight transposes
    xcast_k<<<(T_TOK * DDIM / 8) / 256, 256, 0, stream>>>(x, Xb);
    tcast_k<<<dim3(HDIM / 64, DDIM / 64, EEXP), 256, 0, stream>>>(w1, W1t, DDIM, HDIM);
    tcast_k<<<dim3(HDIM / 64, DDIM / 64, EEXP), 256, 0, stream>>>(w3, W3t, DDIM, HDIM);
    tcast_k<<<dim3(HSDIM / 64, DDIM / 64, 1), 256, 0, stream>>>(sw1, sw1t, DDIM, HSDIM);
    tcast_k<<<dim3(HSDIM / 64, DDIM / 64, 1), 256, 0, stream>>>(sw3, sw3t, DDIM, HSDIM);
    tcast_k<<<dim3(DDIM / 64, HSDIM / 64, 1), 256, 0, stream>>>(sw2, sw2t, HSDIM, DDIM);

    // up-projection (routed z=0..7 + shared z=8)
    fused_up<<<dim3(HDIM / 64, T_TOK / 128, EEXP + 1), 256, 0, stream>>>(
        Xb, rows_token, offsets, W1t, W3t, sw1t, sw3t, Hg, Hs);

    // W2 transpose (into aliased region, after fused_up is done with W1t)
    tcast_k<<<dim3(DDIM / 64, HDIM / 64, EEXP), 256, 0, stream>>>(w2, W2t, HDIM, DDIM);

    // down-projection (routed -> Yg, shared -> out direct)
    gemm2<<<dim3(DDIM / 128, T_TOK / 64, EEXP + 1), 256, 0, stream>>>(
        Hg, Hs, W2t, sw2t, offsets, Yg, out);

    // out = shared + g0*y0 + g1*y1
    combine_k<<<(T_TOK * DDIM / 4) / 256, 256, 0, stream>>>(out, Yg, rowof, topw);
}

// Round 3
// 318.720 us; speedup vs baseline: 1.5402x; 1.0524x over previous
//
#include <hip/hip_runtime.h>
#include <hip/hip_bf16.h>

// Problem constants
#define T_TOK 2048      // B*S
#define DDIM  1024
#define EEXP  8
#define KTOP  2
#define HDIM  2816
#define HSDIM 1536
#define BK    64
#define MT    128       // GEMM m-tile

typedef float f32x4 __attribute__((ext_vector_type(4)));
typedef short bf16x8 __attribute__((ext_vector_type(8)));

__device__ __forceinline__ unsigned short f2bf(float f) {
    __hip_bfloat16 h = __float2bfloat16(f);
    return __builtin_bit_cast(unsigned short, h);
}

// async global->LDS, 16B per lane; LDS dest = wave-uniform base + lane*16
__device__ __forceinline__ void gload16(const unsigned short* g, unsigned short* l) {
    __builtin_amdgcn_global_load_lds(
        (const __attribute__((address_space(1))) unsigned int*)g,
        (__attribute__((address_space(3))) unsigned int*)l, 16, 0, 0);
}

// ---------------- small routing kernels ----------------

__global__ void init_k(int* counts, int* cursors) {
    if (threadIdx.x < EEXP) { counts[threadIdx.x] = 0; cursors[threadIdx.x] = 0; }
}

// one wave per token: 8 experts x 8 lane-chunks over D=1024
__global__ void gate_k(const float* __restrict__ X, const float* __restrict__ GW,
                       int* __restrict__ topi, float* __restrict__ topw,
                       int* __restrict__ counts) {
    int lane = threadIdx.x & 63;
    int t = blockIdx.x * 4 + (threadIdx.x >> 6);
    int e  = lane >> 3;
    int c8 = lane & 7;
    const float* xr = X + (size_t)t * DDIM;
    const float* gr = GW + (size_t)e * DDIM;
    float acc = 0.f;
#pragma unroll 8
    for (int j = 0; j < 32; j++) {
        int d = (c8 + 8 * j) * 4;
        float4 xv = *(const float4*)(xr + d);
        float4 gv = *(const float4*)(gr + d);
        acc += xv.x * gv.x + xv.y * gv.y + xv.z * gv.z + xv.w * gv.w;
    }
    acc += __shfl_xor(acc, 1);
    acc += __shfl_xor(acc, 2);
    acc += __shfl_xor(acc, 4);
    float p[8];
#pragma unroll
    for (int q = 0; q < 8; q++) p[q] = __shfl(acc, q * 8);
    float mx = p[0];
#pragma unroll
    for (int q = 1; q < 8; q++) mx = fmaxf(mx, p[q]);
    float s = 0.f;
#pragma unroll
    for (int q = 0; q < 8; q++) { p[q] = expf(p[q] - mx); s += p[q]; }
    float inv = 1.f / s;
#pragma unroll
    for (int q = 0; q < 8; q++) p[q] *= inv;
    float v1 = -1.f; int i1 = 0;
#pragma unroll
    for (int q = 0; q < 8; q++) { if (p[q] > v1) { v1 = p[q]; i1 = q; } }
    float v2 = -1.f; int i2 = 0;
#pragma unroll
    for (int q = 0; q < 8; q++) { if (q != i1 && p[q] > v2) { v2 = p[q]; i2 = q; } }
    if (lane == 0) {
        topi[2 * t] = i1; topi[2 * t + 1] = i2;
        topw[2 * t] = v1; topw[2 * t + 1] = v2;
        atomicAdd(&counts[i1], 1);
        atomicAdd(&counts[i2], 1);
    }
}

// prefix-sum + device-built tile worklist: (e<<16)|m0, e=8 -> shared expert
__global__ void scan_k(const int* __restrict__ counts, int* __restrict__ offsets,
                       int* __restrict__ wl, int* __restrict__ wl_n) {
    if (threadIdx.x == 0) {
        int s = 0;
        for (int e = 0; e < EEXP; e++) { offsets[e] = s; s += counts[e]; }
        offsets[EEXP] = s;
        int n = 0;
        for (int e = 0; e <= EEXP; e++) {
            int Ne = (e == EEXP) ? T_TOK : counts[e];
            for (int m0 = 0; m0 < Ne; m0 += MT) wl[n++] = (e << 16) | m0;
        }
        wl_n[0] = n;   // <= 56
    }
}

__global__ void build_k(const int* __restrict__ topi, const int* __restrict__ offsets,
                        int* __restrict__ cursors, int* __restrict__ rows_token,
                        int* __restrict__ rowof) {
    int t = blockIdx.x * 256 + threadIdx.x;
    if (t >= T_TOK) return;
    for (int k = 0; k < KTOP; k++) {
        int e = topi[2 * t + k];
        int pos = atomicAdd(&cursors[e], 1);
        int r = offsets[e] + pos;
        rows_token[r] = t;
        rowof[2 * t + k] = r;
    }
}

// ---------------- pre-pass: casts & transposes ----------------

__global__ void xcast_k(const float* __restrict__ X, unsigned short* __restrict__ Xb) {
    int i = (blockIdx.x * 256 + threadIdx.x) * 8;
    float4 a = *(const float4*)(X + i);
    float4 b = *(const float4*)(X + i + 4);
    unsigned short o[8] = { f2bf(a.x), f2bf(a.y), f2bf(a.z), f2bf(a.w),
                            f2bf(b.x), f2bf(b.y), f2bf(b.z), f2bf(b.w) };
    *(uint4*)(Xb + i) = *(const uint4*)o;
}

// W [z][K][N] f32 -> Wt [z][N][K] bf16, 128(k) x 64(n) tiles, 4x4 reg transpose
__global__ __launch_bounds__(256) void tcast_k(const float* __restrict__ S,
                                               unsigned short* __restrict__ Dm,
                                               int Kd, int Nn) {
    size_t zoff = (size_t)blockIdx.z * Kd * Nn;
    S += zoff; Dm += zoff;
    int k0 = blockIdx.y * 128, n0 = blockIdx.x * 64;
    __shared__ __align__(16) unsigned short t[64][132];
    int tid = threadIdx.x;
    int nc = (tid & 15) * 4;         // n base 0..60
    int kq = (tid >> 4) * 4;         // k base 0..60
#pragma unroll
    for (int j = 0; j < 2; j++) {
        int kb = j * 64 + kq;
        const float* p0 = S + (size_t)(k0 + kb) * Nn + n0 + nc;
        float4 q0 = *(const float4*)(p0);
        float4 q1 = *(const float4*)(p0 + (size_t)Nn);
        float4 q2 = *(const float4*)(p0 + 2 * (size_t)Nn);
        float4 q3 = *(const float4*)(p0 + 3 * (size_t)Nn);
#pragma unroll
        for (int i = 0; i < 4; i++) {
            unsigned int lo = (unsigned int)f2bf((&q0.x)[i]) | ((unsigned int)f2bf((&q1.x)[i]) << 16);
            unsigned int hi = (unsigned int)f2bf((&q2.x)[i]) | ((unsigned int)f2bf((&q3.x)[i]) << 16);
            *(uint2*)&t[nc + i][kb] = make_uint2(lo, hi);
        }
    }
    __syncthreads();
    int n = tid >> 4;                // 0..15
    int c = (tid & 15) * 8;          // 0..120
#pragma unroll
    for (int j = 0; j < 4; j++) {
        int nn = j * 16 + n;
        uint2 a = *(const uint2*)&t[nn][c];
        uint2 b = *(const uint2*)&t[nn][c + 4];
        uint4 v = make_uint4(a.x, a.y, b.x, b.y);
        *(uint4*)(Dm + (size_t)(n0 + nn) * Kd + k0 + c) = v;
    }
}

// ---------------- fused up-projection: H = silu(X@W1) * (X@W3) ----------------
// tile 128(M) x 128(N), BK=64, 4 waves 2x2, per-wave 64x64 dual-accumulated.
__global__ __launch_bounds__(256, 2) void fused_up(
    const unsigned short* __restrict__ Xb,
    const int* __restrict__ rows_token,
    const int* __restrict__ offsets,
    const unsigned short* __restrict__ W1t,   // [8][H][D] bf16
    const unsigned short* __restrict__ W3t,
    const unsigned short* __restrict__ sw1t,  // [HS][D]
    const unsigned short* __restrict__ sw3t,
    unsigned short* __restrict__ Hg,          // [4096][H]
    unsigned short* __restrict__ Hs,          // [2048][HS]
    const int* __restrict__ wl, const int* __restrict__ wl_n)
{
    int it = blockIdx.y;
    if (it >= wl_n[0]) return;
    int pk = wl[it];
    int z = pk >> 16, m0 = pk & 0xffff;
    bool sh = (z == EEXP);
    int roff, Ne, Nn;
    const unsigned short *w1, *w3;
    unsigned short* Ho;
    if (sh) { roff = 0; Ne = T_TOK; Nn = HSDIM; w1 = sw1t; w3 = sw3t; Ho = Hs; }
    else {
        roff = offsets[z]; Ne = offsets[z + 1] - roff; Nn = HDIM;
        w1 = W1t + (size_t)z * HDIM * DDIM;
        w3 = W3t + (size_t)z * HDIM * DDIM;
        Ho = Hg;
    }
    int n0 = blockIdx.x * 128;
    if (n0 >= Nn) return;

    __shared__ __align__(16) unsigned short As [128 * 64];
    __shared__ __align__(16) unsigned short B1s[128 * 64];
    __shared__ __align__(16) unsigned short B3s[128 * 64];

    int tid = threadIdx.x, lane = tid & 63, wid = tid >> 6;
    int wr = wid >> 1, wc = wid & 1;          // per-wave 64 rows x 64 cols
    int sc = ((lane & 7) ^ (lane >> 3)) * 8;  // inverse-swizzled source chunk

    const unsigned short* pA[4];
    const unsigned short *pB1[4], *pB3[4];
#pragma unroll
    for (int j = 0; j < 4; j++) {
        int lr = (wid * 4 + j) * 8 + (lane >> 3);
        int gr = m0 + lr; if (gr >= Ne) gr = Ne - 1;
        int tok = sh ? gr : rows_token[roff + gr];
        pA[j]  = Xb + (size_t)tok * DDIM + sc;
        pB1[j] = w1 + (size_t)(n0 + lr) * DDIM + sc;
        pB3[j] = w3 + (size_t)(n0 + lr) * DDIM + sc;
    }

    const f32x4 fz = {0.f, 0.f, 0.f, 0.f};
    f32x4 acc1[4][4], acc3[4][4];
#pragma unroll
    for (int mi = 0; mi < 4; mi++)
#pragma unroll
        for (int nj = 0; nj < 4; nj++) { acc1[mi][nj] = fz; acc3[mi][nj] = fz; }

#pragma unroll 1
    for (int ks = 0; ks < DDIM / BK; ks++) {
        __syncthreads();
#pragma unroll
        for (int j = 0; j < 4; j++) gload16(pA[j],  As  + (wid * 4 + j) * 512);
#pragma unroll
        for (int j = 0; j < 4; j++) gload16(pB1[j], B1s + (wid * 4 + j) * 512);
#pragma unroll
        for (int j = 0; j < 4; j++) gload16(pB3[j], B3s + (wid * 4 + j) * 512);
#pragma unroll
        for (int j = 0; j < 4; j++) { pA[j] += BK; pB1[j] += BK; pB3[j] += BK; }
        __syncthreads();
        int r = lane & 15, h = lane >> 4, sw = (lane & 7) << 4;
#pragma unroll
        for (int kk = 0; kk < 2; kk++) {
            int cb = (kk * 64 + h * 16) ^ sw;
            bf16x8 a[4], b1[4], b3[4];
#pragma unroll
            for (int mi = 0; mi < 4; mi++)
                a[mi] = *(const bf16x8*)((const char*)As + (wr * 64 + mi * 16 + r) * 128 + cb);
#pragma unroll
            for (int nj = 0; nj < 4; nj++) {
                b1[nj] = *(const bf16x8*)((const char*)B1s + (wc * 64 + nj * 16 + r) * 128 + cb);
                b3[nj] = *(const bf16x8*)((const char*)B3s + (wc * 64 + nj * 16 + r) * 128 + cb);
            }
#pragma unroll
            for (int mi = 0; mi < 4; mi++)
#pragma unroll
                for (int nj = 0; nj < 4; nj++) {
                    acc1[mi][nj] = __builtin_amdgcn_mfma_f32_16x16x32_bf16(a[mi], b1[nj], acc1[mi][nj], 0, 0, 0);
                    acc3[mi][nj] = __builtin_amdgcn_mfma_f32_16x16x32_bf16(a[mi], b3[nj], acc3[mi][nj], 0, 0, 0);
                }
        }
    }
    int r = lane & 15, h = lane >> 4;
#pragma unroll
    for (int mi = 0; mi < 4; mi++) {
#pragma unroll
        for (int nj = 0; nj < 4; nj++) {
            int col = n0 + wc * 64 + nj * 16 + r;
#pragma unroll
            for (int j = 0; j < 4; j++) {
                int row = wr * 64 + mi * 16 + h * 4 + j;
                if (m0 + row < Ne) {
                    float aa = acc1[mi][nj][j], bb = acc3[mi][nj][j];
                    float hv = (aa / (1.f + expf(-aa))) * bb;
                    Ho[(size_t)(roff + m0 + row) * Nn + col] = f2bf(hv);
                }
            }
        }
    }
}

// ---------------- down-projection: Y = H @ W2 ----------------
// tile 128(M) x 128(N), BK=64, 4 waves 2x2, per-wave 64x64.
__global__ __launch_bounds__(256) void gemm2(
    const unsigned short* __restrict__ Hg,
    const unsigned short* __restrict__ Hs,
    const unsigned short* __restrict__ W2t,   // [8][D][H] bf16
    const unsigned short* __restrict__ sw2t,  // [D][HS]
    const int* __restrict__ offsets,
    float* __restrict__ Yg,
    float* __restrict__ out,
    const int* __restrict__ wl, const int* __restrict__ wl_n)
{
    int it = blockIdx.y;
    if (it >= wl_n[0]) return;
    int pk = wl[it];
    int z = pk >> 16, m0 = pk & 0xffff;
    bool sh = (z == EEXP);
    int roff, Ne, Kd;
    const unsigned short *Ab, *Bb;
    float* Yo;
    if (sh) { roff = 0; Ne = T_TOK; Kd = HSDIM; Ab = Hs; Bb = sw2t; Yo = out; }
    else {
        roff = offsets[z]; Ne = offsets[z + 1] - roff; Kd = HDIM;
        Ab = Hg + (size_t)roff * HDIM;
        Bb = W2t + (size_t)z * DDIM * HDIM;
        Yo = Yg + (size_t)roff * DDIM;
    }
    int n0 = blockIdx.x * 128;

    __shared__ __align__(16) unsigned short As[128 * 64];
    __shared__ __align__(16) unsigned short Bs[128 * 64];

    int tid = threadIdx.x, lane = tid & 63, wid = tid >> 6;
    int wr = wid >> 1, wc = wid & 1;
    int sc = ((lane & 7) ^ (lane >> 3)) * 8;

    const unsigned short* pA[4];
    const unsigned short* pB[4];
#pragma unroll
    for (int j = 0; j < 4; j++) {
        int lr = (wid * 4 + j) * 8 + (lane >> 3);
        int gr = m0 + lr; if (gr >= Ne) gr = Ne - 1;
        pA[j] = Ab + (size_t)gr * Kd + sc;
        pB[j] = Bb + (size_t)(n0 + lr) * Kd + sc;
    }

    const f32x4 fz = {0.f, 0.f, 0.f, 0.f};
    f32x4 acc[4][4];
#pragma unroll
    for (int mi = 0; mi < 4; mi++)
#pragma unroll
        for (int nj = 0; nj < 4; nj++) acc[mi][nj] = fz;

    int nks = Kd / BK;
#pragma unroll 1
    for (int ks = 0; ks < nks; ks++) {
        __syncthreads();
#pragma unroll
        for (int j = 0; j < 4; j++) gload16(pA[j], As + (wid * 4 + j) * 512);
#pragma unroll
        for (int j = 0; j < 4; j++) gload16(pB[j], Bs + (wid * 4 + j) * 512);
#pragma unroll
        for (int j = 0; j < 4; j++) { pA[j] += BK; pB[j] += BK; }
        __syncthreads();
        int r = lane & 15, h = lane >> 4, sw = (lane & 7) << 4;
#pragma unroll
        for (int kk = 0; kk < 2; kk++) {
            int cb = (kk * 64 + h * 16) ^ sw;
            bf16x8 a[4], b[4];
#pragma unroll
            for (int mi = 0; mi < 4; mi++)
                a[mi] = *(const bf16x8*)((const char*)As + (wr * 64 + mi * 16 + r) * 128 + cb);
#pragma unroll
            for (int nj = 0; nj < 4; nj++)
                b[nj] = *(const bf16x8*)((const char*)Bs + (wc * 64 + nj * 16 + r) * 128 + cb);
#pragma unroll
            for (int mi = 0; mi < 4; mi++)
#pragma unroll
                for (int nj = 0; nj < 4; nj++)
                    acc[mi][nj] = __builtin_amdgcn_mfma_f32_16x16x32_bf16(a[mi], b[nj], acc[mi][nj], 0, 0, 0);
        }
    }
    int r = lane & 15, h = lane >> 4;
#pragma unroll
    for (int mi = 0; mi < 4; mi++) {
#pragma unroll
        for (int nj = 0; nj < 4; nj++) {
            int col = n0 + wc * 64 + nj * 16 + r;
#pragma unroll
            for (int j = 0; j < 4; j++) {
                int row = wr * 64 + mi * 16 + h * 4 + j;
                if (m0 + row < Ne)
                    Yo[(size_t)(m0 + row) * DDIM + col] = acc[mi][nj][j];
            }
        }
    }
}

// ---------------- final combine ----------------
__global__ void combine_k(float* __restrict__ out, const float* __restrict__ Yg,
                          const int* __restrict__ rowof, const float* __restrict__ topw) {
    int idx = blockIdx.x * 256 + threadIdx.x;
    int t = idx >> 8;
    int dq = (idx & 255) << 2;
    int r0 = rowof[2 * t], r1 = rowof[2 * t + 1];
    float g0 = topw[2 * t], g1 = topw[2 * t + 1];
    float* op = out + (size_t)t * DDIM + dq;
    float4 o = *(float4*)op;
    float4 a = *(const float4*)(Yg + (size_t)r0 * DDIM + dq);
    float4 b = *(const float4*)(Yg + (size_t)r1 * DDIM + dq);
    o.x += g0 * a.x + g1 * b.x;
    o.y += g0 * a.y + g1 * b.y;
    o.z += g0 * a.z + g1 * b.z;
    o.w += g0 * a.w + g1 * b.w;
    *(float4*)op = o;
}

// ---------------- launch ----------------
extern "C" void kernel_launch(void* const* d_in, const int* in_sizes, int n_in,
                              void* d_out, int out_size, void* d_ws, size_t ws_size,
                              hipStream_t stream) {
    const float* x   = (const float*)d_in[0];
    const float* gw  = (const float*)d_in[1];
    const float* w1  = (const float*)d_in[2];
    const float* w3  = (const float*)d_in[3];
    const float* w2  = (const float*)d_in[4];
    const float* sw1 = (const float*)d_in[5];
    const float* sw3 = (const float*)d_in[6];
    const float* sw2 = (const float*)d_in[7];
    float* out = (float*)d_out;
    char* ws = (char*)d_ws;

    const size_t MB = 1048576;
    int*   counts     = (int*)(ws);
    int*   offsets    = (int*)(ws + 64);
    int*   cursors    = (int*)(ws + 128);
    int*   wl_n       = (int*)(ws + 192);
    int*   wl         = (int*)(ws + 256);       // <=56 ints
    int*   topi       = (int*)(ws + 512);
    float* topw       = (float*)(ws + 16896);
    int*   rows_token = (int*)(ws + 33280);
    int*   rowof      = (int*)(ws + 49664);
    unsigned short* Xb   = (unsigned short*)(ws + 1 * MB);    // 4 MB
    unsigned short* sw1t = (unsigned short*)(ws + 6 * MB);    // 3 MB
    unsigned short* sw3t = (unsigned short*)(ws + 9 * MB);    // 3 MB
    unsigned short* sw2t = (unsigned short*)(ws + 12 * MB);   // 3 MB
    unsigned short* Hg   = (unsigned short*)(ws + 16 * MB);   // 22 MB
    float*          Yg   = (float*)(ws + 40 * MB);            // 16 MB
    unsigned short* Hs   = (unsigned short*)(ws + 56 * MB);   // 6 MB
    unsigned short* W1t  = (unsigned short*)(ws + 64 * MB);   // 44 MB
    unsigned short* W3t  = (unsigned short*)(ws + 108 * MB);  // 44 MB (ends 152 MB)
    unsigned short* W2t  = W1t;  // aliased: converted after fused_up consumes W1t

    // routing
    init_k<<<1, 64, 0, stream>>>(counts, cursors);
    gate_k<<<T_TOK / 4, 256, 0, stream>>>(x, gw, topi, topw, counts);
    scan_k<<<1, 64, 0, stream>>>(counts, offsets, wl, wl_n);
    build_k<<<T_TOK / 256, 256, 0, stream>>>(topi, offsets, cursors, rows_token, rowof);

    // pre-pass: bf16 casts + weight transposes
    xcast_k<<<(T_TOK * DDIM / 8) / 256, 256, 0, stream>>>(x, Xb);
    tcast_k<<<dim3(HDIM / 64, DDIM / 128, EEXP), 256, 0, stream>>>(w1, W1t, DDIM, HDIM);
    tcast_k<<<dim3(HDIM / 64, DDIM / 128, EEXP), 256, 0, stream>>>(w3, W3t, DDIM, HDIM);
    tcast_k<<<dim3(HSDIM / 64, DDIM / 128, 1), 256, 0, stream>>>(sw1, sw1t, DDIM, HSDIM);
    tcast_k<<<dim3(HSDIM / 64, DDIM / 128, 1), 256, 0, stream>>>(sw3, sw3t, DDIM, HSDIM);
    tcast_k<<<dim3(DDIM / 64, HSDIM / 128, 1), 256, 0, stream>>>(sw2, sw2t, HSDIM, DDIM);

    // up-projection (worklist covers routed + shared tiles)
    fused_up<<<dim3(HDIM / 128, 56), 256, 0, stream>>>(
        Xb, rows_token, offsets, W1t, W3t, sw1t, sw3t, Hg, Hs, wl, wl_n);

    // W2 transpose (into aliased region, after fused_up is done with W1t)
    tcast_k<<<dim3(DDIM / 64, HDIM / 128, EEXP), 256, 0, stream>>>(w2, W2t, HDIM, DDIM);

    // down-projection (routed -> Yg, shared -> out direct)
    gemm2<<<dim3(DDIM / 128, 56), 256, 0, stream>>>(
        Hg, Hs, W2t, sw2t, offsets, Yg, out, wl, wl_n);

    // out = shared + g0*y0 + g1*y1
    combine_k<<<(T_TOK * DDIM / 4) / 256, 256, 0, stream>>>(out, Yg, rowof, topw);
}